// Round 1
// baseline (833.248 us; speedup 1.0000x reference)
//
#include <hip/hip_runtime.h>
#include <math.h>

#define B_ 4
#define C_ 128
#define H_ 128
#define W_ 128
#define HW_ 16384
#define P_ 65536
#define S_ 8388608   // B*C*H*W elements
#define CPG 8        // channels per group (128/16)

__device__ __forceinline__ float sigmoidf_(float x){ return 1.f/(1.f+__expf(-x)); }
__device__ __forceinline__ float siluf_(float x){ return x*sigmoidf_(x); }

// Permute dyn_w rows from [f*128+c] to interleaved [c*4+f] order (so a scan
// thread reads a,b,c,d as one float4), permute dyn_b likewise, zero stats.
__global__ __launch_bounds__(256) void prep_kernel(const float* __restrict__ dyn_w,
    const float* __restrict__ dyn_b, float* __restrict__ wperm,
    float* __restrict__ bperm, float* __restrict__ stats)
{
  int idx = blockIdx.x*256 + threadIdx.x;
  if (idx < 262144) {
    int k = idx & 127, op = (idx >> 7) & 511, d = idx >> 16;
    int c = op >> 2, f = op & 3;
    wperm[idx] = dyn_w[(size_t)((d*512) + (f*128 + c))*128 + k];
  } else if (idx < 264192) {
    int i2 = idx - 262144;
    int op = i2 & 511, d = i2 >> 9;
    bperm[i2] = dyn_b[d*512 + (op & 3)*128 + (op >> 2)];
  } else if (idx < 264448) {
    stats[idx - 264192] = 0.f;
  }
}

// in_proj: X channels-first [128][16384] per batch, W [128][128], out channels-last.
__global__ __launch_bounds__(256) void gemm_inproj(const float* __restrict__ Xall,
    const float* __restrict__ Wm, float* __restrict__ Out)
{
  __shared__ __align__(16) float Xs[16][64];
  __shared__ __align__(16) float Ws[16][64];
  int b = blockIdx.z;
  const float* X = Xall + ((size_t)b << 21);
  float* Ob = Out + ((size_t)b << 21);
  int ot = blockIdx.x << 6, pt = blockIdx.y << 6;
  int t = threadIdx.x, tx = t & 15, ty = t >> 4;
  int kkl = t >> 4, pi = (t & 15) << 2;
  int r = t >> 2, c4 = (t & 3) << 2;
  float acc[4][4] = {};
  for (int k0 = 0; k0 < 128; k0 += 16) {
    float4 xv = *(const float4*)(X + (size_t)(k0 + kkl)*HW_ + pt + pi);
    float4 wv = *(const float4*)(Wm + ((size_t)(ot + r) << 7) + k0 + c4);
    __syncthreads();
    *(float4*)&Xs[kkl][pi] = xv;
    Ws[c4+0][r]=wv.x; Ws[c4+1][r]=wv.y; Ws[c4+2][r]=wv.z; Ws[c4+3][r]=wv.w;
    __syncthreads();
    #pragma unroll
    for (int kk = 0; kk < 16; ++kk) {
      const float4 a = *(const float4*)&Xs[kk][tx << 2];
      const float4 w4 = *(const float4*)&Ws[kk][ty << 2];
      acc[0][0]+=a.x*w4.x; acc[0][1]+=a.x*w4.y; acc[0][2]+=a.x*w4.z; acc[0][3]+=a.x*w4.w;
      acc[1][0]+=a.y*w4.x; acc[1][1]+=a.y*w4.y; acc[1][2]+=a.y*w4.z; acc[1][3]+=a.y*w4.w;
      acc[2][0]+=a.z*w4.x; acc[2][1]+=a.z*w4.y; acc[2][2]+=a.z*w4.z; acc[2][3]+=a.z*w4.w;
      acc[3][0]+=a.w*w4.x; acc[3][1]+=a.w*w4.y; acc[3][2]+=a.w*w4.z; acc[3][3]+=a.w*w4.w;
    }
  }
  int oc = ot + (ty << 2);
  #pragma unroll
  for (int i = 0; i < 4; ++i) {
    float4 o4 = make_float4(acc[i][0], acc[i][1], acc[i][2], acc[i][3]);
    *(float4*)(Ob + ((size_t)(pt + (tx << 2) + i) << 7) + oc) = o4;
  }
}

// Generic NT GEMM: X channels-last [P][128], W [O][128], Out [P][O], K=128.
template<int BIAS, int SIG>
__global__ __launch_bounds__(256) void gemm_cl(const float* __restrict__ X,
    const float* __restrict__ Wm, const float* __restrict__ bias,
    float* __restrict__ Out, int O)
{
  __shared__ __align__(16) float Xs[16][64];
  __shared__ __align__(16) float Ws[16][64];
  int ot = blockIdx.x << 6, pt = blockIdx.y << 6;
  int t = threadIdx.x, tx = t & 15, ty = t >> 4;
  int r = t >> 2, c4 = (t & 3) << 2;
  float acc[4][4] = {};
  const float* xg = X + ((size_t)(pt + r) << 7) + c4;
  const float* wg = Wm + ((size_t)(ot + r) << 7) + c4;
  for (int k0 = 0; k0 < 128; k0 += 16) {
    float4 xv = *(const float4*)(xg + k0);
    float4 wv = *(const float4*)(wg + k0);
    __syncthreads();
    Xs[c4+0][r]=xv.x; Xs[c4+1][r]=xv.y; Xs[c4+2][r]=xv.z; Xs[c4+3][r]=xv.w;
    Ws[c4+0][r]=wv.x; Ws[c4+1][r]=wv.y; Ws[c4+2][r]=wv.z; Ws[c4+3][r]=wv.w;
    __syncthreads();
    #pragma unroll
    for (int kk = 0; kk < 16; ++kk) {
      const float4 a = *(const float4*)&Xs[kk][tx << 2];
      const float4 w4 = *(const float4*)&Ws[kk][ty << 2];
      acc[0][0]+=a.x*w4.x; acc[0][1]+=a.x*w4.y; acc[0][2]+=a.x*w4.z; acc[0][3]+=a.x*w4.w;
      acc[1][0]+=a.y*w4.x; acc[1][1]+=a.y*w4.y; acc[1][2]+=a.y*w4.z; acc[1][3]+=a.y*w4.w;
      acc[2][0]+=a.z*w4.x; acc[2][1]+=a.z*w4.y; acc[2][2]+=a.z*w4.z; acc[2][3]+=a.z*w4.w;
      acc[3][0]+=a.w*w4.x; acc[3][1]+=a.w*w4.y; acc[3][2]+=a.w*w4.z; acc[3][3]+=a.w*w4.w;
    }
  }
  int oc = ot + (ty << 2);
  float4 bv = make_float4(0.f, 0.f, 0.f, 0.f);
  if (BIAS) bv = *(const float4*)(bias + oc);
  #pragma unroll
  for (int i = 0; i < 4; ++i) {
    float4 o4 = make_float4(acc[i][0]+bv.x, acc[i][1]+bv.y, acc[i][2]+bv.z, acc[i][3]+bv.w);
    if (SIG) { o4.x = sigmoidf_(o4.x); o4.y = sigmoidf_(o4.y); o4.z = sigmoidf_(o4.z); o4.w = sigmoidf_(o4.w); }
    *(float4*)(Out + (size_t)(pt + (tx << 2) + i)*(size_t)O + oc) = o4;
  }
}

// GroupNorm stats: partial sums per (b,g) over chunks, atomics into stats[0:64]=sum, [64:128]=sumsq.
__global__ __launch_bounds__(256) void gn_stats(const float* __restrict__ X,
    float* __restrict__ stats)
{
  int bg = blockIdx.x, chunk = blockIdx.y;
  int b = bg >> 4, g = bg & 15;
  int t = threadIdx.x;
  int c = t & 7, pr = t >> 3;
  const float* base = X + ((size_t)b << 21) + (g << 3) + c;
  int p0 = chunk << 10;
  float s = 0.f, s2 = 0.f;
  for (int i = 0; i < 32; ++i) {
    float v = base[(size_t)(p0 + (i << 5) + pr) << 7];
    s += v; s2 += v*v;
  }
  #pragma unroll
  for (int off = 32; off; off >>= 1) { s += __shfl_down(s, off); s2 += __shfl_down(s2, off); }
  __shared__ float ls[8];
  int wv = t >> 6, lane = t & 63;
  if (lane == 0) { ls[wv] = s; ls[4 + wv] = s2; }
  __syncthreads();
  if (t == 0) {
    atomicAdd(&stats[bg], ls[0]+ls[1]+ls[2]+ls[3]);
    atomicAdd(&stats[64+bg], ls[4]+ls[5]+ls[6]+ls[7]);
  }
}

// Apply GN + SiLU in place (channels-last).
__global__ __launch_bounds__(256) void gn_apply(float* __restrict__ X,
    const float* __restrict__ stats, const float* __restrict__ gamma,
    const float* __restrict__ beta)
{
  int i4 = blockIdx.x*256 + threadIdx.x;
  size_t base = (size_t)i4 << 2;
  int c4 = (int)(base & 127);
  size_t p = base >> 7;
  int b = (int)(p >> 14);
  int g = c4 >> 3;
  const float cnt = (float)(CPG*HW_);
  float mu = stats[b*16+g]/cnt;
  float var = stats[64+b*16+g]/cnt - mu*mu;
  float rs = rsqrtf(var + 1e-5f);
  float4 v = *(float4*)(X + base);
  v.x = siluf_((v.x-mu)*rs*gamma[c4+0]+beta[c4+0]);
  v.y = siluf_((v.y-mu)*rs*gamma[c4+1]+beta[c4+1]);
  v.z = siluf_((v.z-mu)*rs*gamma[c4+2]+beta[c4+2]);
  v.w = siluf_((v.w-mu)*rs*gamma[c4+3]+beta[c4+3]);
  *(float4*)(X + base) = v;
}

// Directional scan. coeff [nb*16384][512] (interleaved c*4+f), xp/fused [65536][128].
template<int AXIS_W, int REV, int FIRST>
__global__ __launch_bounds__(128) void scan_kernel(const float* __restrict__ coeff,
    const float* __restrict__ xp, float* __restrict__ fused, int b0)
{
  int c = threadIdx.x;
  int blk = blockIdx.x;
  int brel = blk >> 7, line = blk & 127;
  float h = 0.f;
  #pragma unroll 4
  for (int s = 0; s < 128; ++s) {
    int tt = REV ? 127 - s : s;
    int prel = (AXIS_W ? (line << 7) + tt : (tt << 7) + line) + (brel << 14);
    int pg = prel + (b0 << 14);
    float4 co = *(const float4*)(coeff + ((size_t)prel << 9) + (c << 2));
    float x = xp[((size_t)pg << 7) + c];
    float a = sigmoidf_(co.x);
    h = a*h + co.y*x;
    float y = co.z*h + co.w*x;
    float* fp = fused + ((size_t)pg << 7) + c;
    if (FIRST) *fp = 0.25f*y;
    else       *fp += 0.25f*y;
  }
}

__global__ __launch_bounds__(256) void zmul(float* __restrict__ Bf, const float* __restrict__ G)
{
  int i4 = blockIdx.x*256 + threadIdx.x;
  size_t base = (size_t)i4 << 2;
  float4 a = *(float4*)(Bf + base);
  float4 g = *(const float4*)(G + base);
  a.x *= g.x; a.y *= g.y; a.z *= g.z; a.w *= g.w;
  *(float4*)(Bf + base) = a;
}

// Depthwise 3x3, channels-last, zero padding.
__global__ __launch_bounds__(256) void dwconv(const float* __restrict__ Z,
    const float* __restrict__ K9, float* __restrict__ Outp)
{
  __shared__ float kk[1152];
  int t = threadIdx.x;
  for (int i = t; i < 1152; i += 256) kk[i] = K9[i];
  __syncthreads();
  int i4 = blockIdx.x*256 + t;
  size_t base = (size_t)i4 << 2;
  int c0 = (int)(base & 127);
  size_t p = base >> 7;
  int w = (int)(p & 127), h = (int)((p >> 7) & 127), b = (int)(p >> 14);
  float4 acc = make_float4(0.f,0.f,0.f,0.f);
  #pragma unroll
  for (int di = 0; di < 3; ++di) {
    int hy = h + di - 1;
    if ((unsigned)hy > 127u) continue;
    #pragma unroll
    for (int dj = 0; dj < 3; ++dj) {
      int wx = w + dj - 1;
      if ((unsigned)wx > 127u) continue;
      size_t p2 = ((size_t)b << 14) + (hy << 7) + wx;
      float4 v = *(const float4*)(Z + (p2 << 7) + c0);
      int o = di*3 + dj;
      acc.x += v.x * kk[c0*9 + o];
      acc.y += v.y * kk[(c0+1)*9 + o];
      acc.z += v.z * kk[(c0+2)*9 + o];
      acc.w += v.w * kk[(c0+3)*9 + o];
    }
  }
  *(float4*)(Outp + base) = acc;
}

// GN2 apply + SiLU + transpose to channels-first output.
__global__ __launch_bounds__(256) void gn_final(const float* __restrict__ Z,
    const float* __restrict__ stats, const float* __restrict__ gamma,
    const float* __restrict__ beta, float* __restrict__ out)
{
  __shared__ float ls[32][129];
  int w0 = blockIdx.x << 5, hh = blockIdx.y, b = blockIdx.z;
  size_t p0 = ((size_t)b << 14) + (hh << 7) + w0;
  int t = threadIdx.x;
  const float cnt = (float)(CPG*HW_);
  #pragma unroll
  for (int i = 0; i < 4; ++i) {
    int l = t + i*256;
    int row = l >> 5, c4 = (l & 31) << 2;
    float4 v = *(const float4*)(Z + ((p0 + row) << 7) + c4);
    int g = c4 >> 3;
    float mu = stats[b*16+g]/cnt;
    float var = stats[64+b*16+g]/cnt - mu*mu;
    float rs = rsqrtf(var + 1e-5f);
    float vals[4] = {v.x, v.y, v.z, v.w};
    #pragma unroll
    for (int j = 0; j < 4; ++j) {
      float nv = (vals[j]-mu)*rs*gamma[c4+j] + beta[c4+j];
      ls[row][c4+j] = siluf_(nv);
    }
  }
  __syncthreads();
  int ww = t & 31, c0 = t >> 5;
  #pragma unroll
  for (int cc = c0; cc < 128; cc += 8) {
    out[(((size_t)(b*128 + cc)) << 14) + (hh << 7) + (w0 + ww)] = ls[ww][cc];
  }
}

extern "C" void kernel_launch(void* const* d_in, const int* in_sizes, int n_in,
                              void* d_out, int out_size, void* d_ws, size_t ws_size,
                              hipStream_t stream)
{
  (void)in_sizes; (void)n_in; (void)out_size;
  const float* x      = (const float*)d_in[0];
  const float* w_in   = (const float*)d_in[1];
  const float* g1g    = (const float*)d_in[2];
  const float* g1b    = (const float*)d_in[3];
  const float* w_gate = (const float*)d_in[4];
  const float* b_gate = (const float*)d_in[5];
  const float* dyn_w  = (const float*)d_in[6];
  const float* dyn_b  = (const float*)d_in[7];
  const float* dwk    = (const float*)d_in[8];
  const float* w_out  = (const float*)d_in[9];
  const float* g2g    = (const float*)d_in[10];
  const float* g2b    = (const float*)d_in[11];
  float* out = (float*)d_out;

  float* A  = (float*)d_ws;   // [65536][128]: xp_raw -> xp -> (later) zout
  float* Bf = A + S_;         // [65536][128]: fused -> z (in place)
  float* Cc = Bf + S_;        // coeff region (nb*S) -> gate -> zdw
  int nb = 4;
  while (nb > 1 && ((size_t)(2 + nb)*S_ + 264448)*4 > ws_size) nb >>= 1;
  float* wperm = Cc + (size_t)nb*S_;   // 262144
  float* bperm = wperm + 262144;       // 2048
  float* stats = bperm + 2048;         // 256: [s1 64][q1 64][s2 64][q2 64]

  prep_kernel<<<1033, 256, 0, stream>>>(dyn_w, dyn_b, wperm, bperm, stats);
  gemm_inproj<<<dim3(2, 256, 4), 256, 0, stream>>>(x, w_in, A);
  gn_stats<<<dim3(64, 16), 256, 0, stream>>>(A, stats);
  gn_apply<<<8192, 256, 0, stream>>>(A, stats, g1g, g1b);

  for (int d = 0; d < 4; ++d) {
    for (int b0 = 0; b0 < 4; b0 += nb) {
      gemm_cl<1,0><<<dim3(8, nb*256), 256, 0, stream>>>(A + ((size_t)b0 << 21),
          wperm + (size_t)d*65536, bperm + d*512, Cc, 512);
      dim3 sg(nb*128);
      switch (d) {
        case 0: scan_kernel<1,0,1><<<sg,128,0,stream>>>(Cc, A, Bf, b0); break;
        case 1: scan_kernel<1,1,0><<<sg,128,0,stream>>>(Cc, A, Bf, b0); break;
        case 2: scan_kernel<0,0,0><<<sg,128,0,stream>>>(Cc, A, Bf, b0); break;
        case 3: scan_kernel<0,1,0><<<sg,128,0,stream>>>(Cc, A, Bf, b0); break;
      }
    }
  }

  gemm_cl<1,1><<<dim3(2, 1024), 256, 0, stream>>>(A, w_gate, b_gate, Cc, 128);
  zmul<<<8192, 256, 0, stream>>>(Bf, Cc);
  dwconv<<<8192, 256, 0, stream>>>(Bf, dwk, Cc);
  gemm_cl<0,0><<<dim3(2, 1024), 256, 0, stream>>>(Cc, w_out, nullptr, A, 128);
  gn_stats<<<dim3(64, 16), 256, 0, stream>>>(A, stats + 128);
  gn_final<<<dim3(4, 128, 4), 256, 0, stream>>>(A, stats + 128, g2g, g2b, out);
}

// Round 2
// 412.771 us; speedup vs baseline: 2.0187x; 2.0187x over previous
//
#include <hip/hip_runtime.h>
#include <math.h>

#define B_ 4
#define C_ 128
#define H_ 128
#define W_ 128
#define HW_ 16384
#define P_ 65536
#define S_ 8388608   // B*C*H*W elements
#define CPG 8        // channels per group (128/16)

typedef unsigned short u16;
typedef __attribute__((ext_vector_type(8))) short short8;
typedef __attribute__((ext_vector_type(4))) float f32x4;

__device__ __forceinline__ float sigmoidf_(float x){ return 1.f/(1.f+__expf(-x)); }
__device__ __forceinline__ float siluf_(float x){ return x*sigmoidf_(x); }
__device__ __forceinline__ u16 f2bf(float f){
  unsigned x = __float_as_uint(f);
  return (u16)((x + 0x7fffu + ((x >> 16) & 1u)) >> 16);
}
__device__ __forceinline__ float b2f(u16 u){ return __uint_as_float(((unsigned)u) << 16); }

// Permute dyn_w rows to interleaved [c*4+f] order (bf16), permute dyn_b,
// convert w_gate/w_out to bf16, zero stats.
__global__ __launch_bounds__(256) void prep_kernel(const float* __restrict__ dyn_w,
    const float* __restrict__ dyn_b, const float* __restrict__ w_gate,
    const float* __restrict__ w_out, u16* __restrict__ wpermb,
    float* __restrict__ bperm, u16* __restrict__ wgbf, u16* __restrict__ wobf,
    float* __restrict__ stats)
{
  int idx = blockIdx.x*256 + threadIdx.x;
  if (idx < 262144) {
    int k = idx & 127, op = (idx >> 7) & 511, d = idx >> 16;
    int c = op >> 2, f = op & 3;
    wpermb[idx] = f2bf(dyn_w[(size_t)((d*512) + (f*128 + c))*128 + k]);
  } else if (idx < 264192) {
    int i2 = idx - 262144;
    int op = i2 & 511, d = i2 >> 9;
    bperm[i2] = dyn_b[d*512 + (op & 3)*128 + (op >> 2)];
  } else if (idx < 280576) {
    int i2 = idx - 264192;
    wgbf[i2] = f2bf(w_gate[i2]);
  } else if (idx < 296960) {
    int i2 = idx - 280576;
    wobf[i2] = f2bf(w_out[i2]);
  } else if (idx < 297216) {
    stats[idx - 296960] = 0.f;
  }
}

// in_proj: X channels-first [128][16384] per batch, W [128][128], out channels-last fp32.
__global__ __launch_bounds__(256) void gemm_inproj(const float* __restrict__ Xall,
    const float* __restrict__ Wm, float* __restrict__ Out)
{
  __shared__ __align__(16) float Xs[16][64];
  __shared__ __align__(16) float Ws[16][64];
  int b = blockIdx.z;
  const float* X = Xall + ((size_t)b << 21);
  float* Ob = Out + ((size_t)b << 21);
  int ot = blockIdx.x << 6, pt = blockIdx.y << 6;
  int t = threadIdx.x, tx = t & 15, ty = t >> 4;
  int kkl = t >> 4, pi = (t & 15) << 2;
  int r = t >> 2, c4 = (t & 3) << 2;
  float acc[4][4] = {};
  for (int k0 = 0; k0 < 128; k0 += 16) {
    float4 xv = *(const float4*)(X + (size_t)(k0 + kkl)*HW_ + pt + pi);
    float4 wv = *(const float4*)(Wm + ((size_t)(ot + r) << 7) + k0 + c4);
    __syncthreads();
    *(float4*)&Xs[kkl][pi] = xv;
    Ws[c4+0][r]=wv.x; Ws[c4+1][r]=wv.y; Ws[c4+2][r]=wv.z; Ws[c4+3][r]=wv.w;
    __syncthreads();
    #pragma unroll
    for (int kk = 0; kk < 16; ++kk) {
      const float4 a = *(const float4*)&Xs[kk][tx << 2];
      const float4 w4 = *(const float4*)&Ws[kk][ty << 2];
      acc[0][0]+=a.x*w4.x; acc[0][1]+=a.x*w4.y; acc[0][2]+=a.x*w4.z; acc[0][3]+=a.x*w4.w;
      acc[1][0]+=a.y*w4.x; acc[1][1]+=a.y*w4.y; acc[1][2]+=a.y*w4.z; acc[1][3]+=a.y*w4.w;
      acc[2][0]+=a.z*w4.x; acc[2][1]+=a.z*w4.y; acc[2][2]+=a.z*w4.z; acc[2][3]+=a.z*w4.w;
      acc[3][0]+=a.w*w4.x; acc[3][1]+=a.w*w4.y; acc[3][2]+=a.w*w4.z; acc[3][3]+=a.w*w4.w;
    }
  }
  int oc = ot + (ty << 2);
  #pragma unroll
  for (int i = 0; i < 4; ++i) {
    float4 o4 = make_float4(acc[i][0], acc[i][1], acc[i][2], acc[i][3]);
    *(float4*)(Ob + ((size_t)(pt + (tx << 2) + i) << 7) + oc) = o4;
  }
}

// MFMA NT GEMM: X bf16 [P][128], W bf16 [OO][128], Out bf16 [P][OO], K=128.
// Block = 256 thr (4 waves); wave = 64 pos x 64 cols; grid (Pchunk/256, OO/64).
// No LDS. A/B fragments are contiguous bf16x8 k-slices loaded straight from global.
template<int OO, int BIAS, int SIG>
__global__ __launch_bounds__(256) void mfma_nt(const u16* __restrict__ X,
    const u16* __restrict__ Wm, const float* __restrict__ bias, u16* __restrict__ Out)
{
  int wv = threadIdx.x >> 6, lane = threadIdx.x & 63;
  int pt = blockIdx.x*256 + wv*64;
  int ot = blockIdx.y*64;
  int m = lane & 15, kg = lane >> 4;    // A row / B col within tile; k-group
  short8 Af[4][4];
  #pragma unroll
  for (int rt = 0; rt < 4; ++rt) {
    const u16* ar = X + ((size_t)(pt + rt*16 + m) << 7) + kg*8;
    #pragma unroll
    for (int kk = 0; kk < 4; ++kk)
      Af[rt][kk] = *(const short8*)(ar + kk*32);
  }
  f32x4 acc[4][4];
  #pragma unroll
  for (int rt = 0; rt < 4; ++rt)
    #pragma unroll
    for (int ct = 0; ct < 4; ++ct)
      acc[rt][ct] = (f32x4){0.f, 0.f, 0.f, 0.f};
  #pragma unroll
  for (int ct = 0; ct < 4; ++ct) {
    const u16* wr = Wm + ((size_t)(ot + ct*16 + m) << 7) + kg*8;
    short8 Bf[4];
    #pragma unroll
    for (int kk = 0; kk < 4; ++kk)
      Bf[kk] = *(const short8*)(wr + kk*32);
    #pragma unroll
    for (int rt = 0; rt < 4; ++rt)
      #pragma unroll
      for (int kk = 0; kk < 4; ++kk)
        acc[rt][ct] = __builtin_amdgcn_mfma_f32_16x16x32_bf16(Af[rt][kk], Bf[kk], acc[rt][ct], 0, 0, 0);
  }
  #pragma unroll
  for (int ct = 0; ct < 4; ++ct) {
    float bv = BIAS ? bias[ot + ct*16 + m] : 0.f;
    #pragma unroll
    for (int rt = 0; rt < 4; ++rt) {
      #pragma unroll
      for (int r = 0; r < 4; ++r) {
        int row = pt + rt*16 + kg*4 + r;       // D: col=lane&15, row=(lane>>4)*4+r
        int col = ot + ct*16 + m;
        float v = acc[rt][ct][r] + bv;
        if (SIG) v = sigmoidf_(v);
        Out[(size_t)row*OO + col] = f2bf(v);
      }
    }
  }
}

// GroupNorm stats over fp32 channels-last.
__global__ __launch_bounds__(256) void gn_stats(const float* __restrict__ X,
    float* __restrict__ stats)
{
  int bg = blockIdx.x, chunk = blockIdx.y;
  int b = bg >> 4, g = bg & 15;
  int t = threadIdx.x;
  int c = t & 7, pr = t >> 3;
  const float* base = X + ((size_t)b << 21) + (g << 3) + c;
  int p0 = chunk << 10;
  float s = 0.f, s2 = 0.f;
  for (int i = 0; i < 32; ++i) {
    float v = base[(size_t)(p0 + (i << 5) + pr) << 7];
    s += v; s2 += v*v;
  }
  #pragma unroll
  for (int off = 32; off; off >>= 1) { s += __shfl_down(s, off); s2 += __shfl_down(s2, off); }
  __shared__ float ls[8];
  int wv = t >> 6, lane = t & 63;
  if (lane == 0) { ls[wv] = s; ls[4 + wv] = s2; }
  __syncthreads();
  if (t == 0) {
    atomicAdd(&stats[bg], ls[0]+ls[1]+ls[2]+ls[3]);
    atomicAdd(&stats[64+bg], ls[4]+ls[5]+ls[6]+ls[7]);
  }
}

// GroupNorm stats over bf16 channels-last.
__global__ __launch_bounds__(256) void gn_stats_bf(const u16* __restrict__ X,
    float* __restrict__ stats)
{
  int bg = blockIdx.x, chunk = blockIdx.y;
  int b = bg >> 4, g = bg & 15;
  int t = threadIdx.x;
  int c = t & 7, pr = t >> 3;
  const u16* base = X + ((size_t)b << 21) + (g << 3) + c;
  int p0 = chunk << 10;
  float s = 0.f, s2 = 0.f;
  for (int i = 0; i < 32; ++i) {
    float v = b2f(base[(size_t)(p0 + (i << 5) + pr) << 7]);
    s += v; s2 += v*v;
  }
  #pragma unroll
  for (int off = 32; off; off >>= 1) { s += __shfl_down(s, off); s2 += __shfl_down(s2, off); }
  __shared__ float ls[8];
  int wv = t >> 6, lane = t & 63;
  if (lane == 0) { ls[wv] = s; ls[4 + wv] = s2; }
  __syncthreads();
  if (t == 0) {
    atomicAdd(&stats[bg], ls[0]+ls[1]+ls[2]+ls[3]);
    atomicAdd(&stats[64+bg], ls[4]+ls[5]+ls[6]+ls[7]);
  }
}

// Apply GN1 + SiLU: read fp32, write bf16.
__global__ __launch_bounds__(256) void gn_apply(const float* __restrict__ X,
    const float* __restrict__ stats, const float* __restrict__ gamma,
    const float* __restrict__ beta, u16* __restrict__ Xb)
{
  int i4 = blockIdx.x*256 + threadIdx.x;
  size_t base = (size_t)i4 << 2;
  int c4 = (int)(base & 127);
  size_t p = base >> 7;
  int b = (int)(p >> 14);
  int g = c4 >> 3;
  const float cnt = (float)(CPG*HW_);
  float mu = stats[b*16+g]/cnt;
  float var = stats[64+b*16+g]/cnt - mu*mu;
  float rs = rsqrtf(var + 1e-5f);
  float4 v = *(const float4*)(X + base);
  ushort4 o;
  o.x = f2bf(siluf_((v.x-mu)*rs*gamma[c4+0]+beta[c4+0]));
  o.y = f2bf(siluf_((v.y-mu)*rs*gamma[c4+1]+beta[c4+1]));
  o.z = f2bf(siluf_((v.z-mu)*rs*gamma[c4+2]+beta[c4+2]));
  o.w = f2bf(siluf_((v.w-mu)*rs*gamma[c4+3]+beta[c4+3]));
  *(ushort4*)(Xb + base) = o;
}

// Directional scan. coeff bf16 [nb*16384][512] (interleaved c*4+f), xp bf16, fused fp32.
template<int AXIS_W, int REV, int FIRST>
__global__ __launch_bounds__(128) void scan_kernel(const u16* __restrict__ coeff,
    const u16* __restrict__ xp, float* __restrict__ fused, int b0)
{
  int c = threadIdx.x;
  int blk = blockIdx.x;
  int brel = blk >> 7, line = blk & 127;
  float h = 0.f;
  #pragma unroll 8
  for (int s = 0; s < 128; ++s) {
    int tt = REV ? 127 - s : s;
    int prel = (AXIS_W ? (line << 7) + tt : (tt << 7) + line) + (brel << 14);
    int pg = prel + (b0 << 14);
    ushort4 co = *(const ushort4*)(coeff + ((size_t)prel << 9) + (c << 2));
    float x = b2f(xp[((size_t)pg << 7) + c]);
    float a = sigmoidf_(b2f(co.x));
    h = a*h + b2f(co.y)*x;
    float y = b2f(co.z)*h + b2f(co.w)*x;
    float* fp = fused + ((size_t)pg << 7) + c;
    if (FIRST) *fp = 0.25f*y;
    else       *fp += 0.25f*y;
  }
}

// Depthwise 3x3 with fused gate multiply: z = dw3x3(fused * gate), out bf16.
__global__ __launch_bounds__(256) void dwconv(const float* __restrict__ Z,
    const u16* __restrict__ G, const float* __restrict__ K9, u16* __restrict__ Outp)
{
  __shared__ float kk[1152];
  int t = threadIdx.x;
  for (int i = t; i < 1152; i += 256) kk[i] = K9[i];
  __syncthreads();
  int i4 = blockIdx.x*256 + t;
  size_t base = (size_t)i4 << 2;
  int c0 = (int)(base & 127);
  size_t p = base >> 7;
  int w = (int)(p & 127), h = (int)((p >> 7) & 127), b = (int)(p >> 14);
  float4 acc = make_float4(0.f,0.f,0.f,0.f);
  #pragma unroll
  for (int di = 0; di < 3; ++di) {
    int hy = h + di - 1;
    if ((unsigned)hy > 127u) continue;
    #pragma unroll
    for (int dj = 0; dj < 3; ++dj) {
      int wx = w + dj - 1;
      if ((unsigned)wx > 127u) continue;
      size_t p2 = ((size_t)b << 14) + (hy << 7) + wx;
      float4 v = *(const float4*)(Z + (p2 << 7) + c0);
      ushort4 gv = *(const ushort4*)(G + (p2 << 7) + c0);
      int o = di*3 + dj;
      acc.x += v.x * b2f(gv.x) * kk[c0*9 + o];
      acc.y += v.y * b2f(gv.y) * kk[(c0+1)*9 + o];
      acc.z += v.z * b2f(gv.z) * kk[(c0+2)*9 + o];
      acc.w += v.w * b2f(gv.w) * kk[(c0+3)*9 + o];
    }
  }
  ushort4 ov;
  ov.x = f2bf(acc.x); ov.y = f2bf(acc.y); ov.z = f2bf(acc.z); ov.w = f2bf(acc.w);
  *(ushort4*)(Outp + base) = ov;
}

// GN2 apply + SiLU + transpose to channels-first fp32 output. Input bf16.
__global__ __launch_bounds__(256) void gn_final(const u16* __restrict__ Z,
    const float* __restrict__ stats, const float* __restrict__ gamma,
    const float* __restrict__ beta, float* __restrict__ out)
{
  __shared__ float ls[32][129];
  int w0 = blockIdx.x << 5, hh = blockIdx.y, b = blockIdx.z;
  size_t p0 = ((size_t)b << 14) + (hh << 7) + w0;
  int t = threadIdx.x;
  const float cnt = (float)(CPG*HW_);
  #pragma unroll
  for (int i = 0; i < 4; ++i) {
    int l = t + i*256;
    int row = l >> 5, c4 = (l & 31) << 2;
    ushort4 v = *(const ushort4*)(Z + ((p0 + row) << 7) + c4);
    int g = c4 >> 3;
    float mu = stats[b*16+g]/cnt;
    float var = stats[64+b*16+g]/cnt - mu*mu;
    float rs = rsqrtf(var + 1e-5f);
    float vals[4] = {b2f(v.x), b2f(v.y), b2f(v.z), b2f(v.w)};
    #pragma unroll
    for (int j = 0; j < 4; ++j) {
      float nv = (vals[j]-mu)*rs*gamma[c4+j] + beta[c4+j];
      ls[row][c4+j] = siluf_(nv);
    }
  }
  __syncthreads();
  int ww = t & 31, c0 = t >> 5;
  #pragma unroll
  for (int cc = c0; cc < 128; cc += 8) {
    out[(((size_t)(b*128 + cc)) << 14) + (hh << 7) + (w0 + ww)] = ls[ww][cc];
  }
}

extern "C" void kernel_launch(void* const* d_in, const int* in_sizes, int n_in,
                              void* d_out, int out_size, void* d_ws, size_t ws_size,
                              hipStream_t stream)
{
  (void)in_sizes; (void)n_in; (void)out_size;
  const float* x      = (const float*)d_in[0];
  const float* w_in   = (const float*)d_in[1];
  const float* g1g    = (const float*)d_in[2];
  const float* g1b    = (const float*)d_in[3];
  const float* w_gate = (const float*)d_in[4];
  const float* b_gate = (const float*)d_in[5];
  const float* dyn_w  = (const float*)d_in[6];
  const float* dyn_b  = (const float*)d_in[7];
  const float* dwk    = (const float*)d_in[8];
  const float* w_out  = (const float*)d_in[9];
  const float* g2g    = (const float*)d_in[10];
  const float* g2b    = (const float*)d_in[11];
  float* out = (float*)d_out;

  // workspace layout (bytes)
  char* p0 = (char*)d_ws;
  float* A    = (float*)p0;                       // S_ fp32: xp_raw; later Zdw/Zout bf16
  float* Bfp  = (float*)(p0 + (size_t)S_*4);      // S_ fp32: fused
  u16*   Abf  = (u16*)(p0 + (size_t)S_*8);        // S_ bf16: xp
  u16*   coeff= (u16*)(p0 + (size_t)S_*10);       // nb*S_ bf16: per-chunk coeffs
  // pick nb (batches per coeff chunk)
  size_t fixed = (size_t)S_*10 + (size_t)(262144 + 16384 + 16384)*2 + (size_t)(2048 + 256)*4;
  int nb = 4;
  while (nb > 1 && fixed + (size_t)nb*S_*2 > ws_size) nb >>= 1;
  char* pw = p0 + (size_t)S_*10 + (size_t)nb*S_*2;
  u16*   wpermb = (u16*)pw;                       // 262144
  u16*   wgbf   = wpermb + 262144;                // 16384
  u16*   wobf   = wgbf + 16384;                   // 16384
  float* bperm  = (float*)(wobf + 16384);         // 2048
  float* stats  = bperm + 2048;                   // 256
  u16*   Gbf    = coeff;                          // aliases coeff region (free after scans)
  u16*   Zdw    = (u16*)A;                        // aliases A (free after gn_apply)
  u16*   Zout   = (u16*)A + S_;                   // second half of A region

  prep_kernel<<<1161, 256, 0, stream>>>(dyn_w, dyn_b, w_gate, w_out,
                                        wpermb, bperm, wgbf, wobf, stats);
  gemm_inproj<<<dim3(2, 256, 4), 256, 0, stream>>>(x, w_in, A);
  gn_stats<<<dim3(64, 16), 256, 0, stream>>>(A, stats);
  gn_apply<<<8192, 256, 0, stream>>>(A, stats, g1g, g1b, Abf);

  for (int d = 0; d < 4; ++d) {
    for (int b0 = 0; b0 < 4; b0 += nb) {
      mfma_nt<512,1,0><<<dim3(nb*64, 8), 256, 0, stream>>>(
          Abf + ((size_t)b0 << 21), wpermb + (size_t)d*65536, bperm + d*512, coeff);
      dim3 sg(nb*128);
      switch (d) {
        case 0: scan_kernel<1,0,1><<<sg,128,0,stream>>>(coeff, Abf, Bfp, b0); break;
        case 1: scan_kernel<1,1,0><<<sg,128,0,stream>>>(coeff, Abf, Bfp, b0); break;
        case 2: scan_kernel<0,0,0><<<sg,128,0,stream>>>(coeff, Abf, Bfp, b0); break;
        case 3: scan_kernel<0,1,0><<<sg,128,0,stream>>>(coeff, Abf, Bfp, b0); break;
      }
    }
  }

  mfma_nt<128,1,1><<<dim3(256, 2), 256, 0, stream>>>(Abf, wgbf, b_gate, Gbf);
  dwconv<<<8192, 256, 0, stream>>>(Bfp, Gbf, dwk, Zdw);
  mfma_nt<128,0,0><<<dim3(256, 2), 256, 0, stream>>>(Zdw, wobf, nullptr, Zout);
  gn_stats_bf<<<dim3(64, 16), 256, 0, stream>>>(Zout, stats + 128);
  gn_final<<<dim3(4, 128, 4), 256, 0, stream>>>(Zout, stats + 128, g2g, g2b, out);
}